// Round 4
// baseline (328.797 us; speedup 1.0000x reference)
//
#include <hip/hip_runtime.h>

#define B  8
#define N  8192
#define M  2048
#define C  64
#define CT 64
#define K  32
#define R2 0.04f   // nearest f32 to 0.2*0.2, matches jnp/np promotion

// clang-native vector types: __builtin_nontemporal_* rejects HIP_vector_type
typedef __attribute__((ext_vector_type(4))) float f4;
typedef __attribute__((ext_vector_type(4))) int   i4;

__device__ __forceinline__ float rfl(float x) {
    union { float f; int i; } u;
    u.f = x;
    u.i = __builtin_amdgcn_readfirstlane(u.i);
    return u.f;
}

// one 64-point chunk. d2 replicates np op order exactly:
// (cn + pn) - 2*cross, no fma contraction. pn^2 precomputed in vv.w.
// Verbatim (correctness-verified since R0). Extra invocations after
// cnt >= K are no-ops (slot >= K never writes), so exit granularity is
// semantics-free.
#define PROC(vv, nn)                                                          \
    do {                                                                      \
        const float cross = __fadd_rn(                                        \
            __fadd_rn(__fmul_rn(cx, (vv).x), __fmul_rn(cy, (vv).y)),          \
            __fmul_rn(cz, (vv).z));                                           \
        const float d2 = __fsub_rn(__fadd_rn(cn, (vv).w),                     \
                                   __fmul_rn(2.0f, cross));                   \
        const bool valid = d2 < R2;                                           \
        const unsigned long long mask = __ballot(valid);                      \
        if (valid) {                                                          \
            const int slot = cnt + __builtin_amdgcn_mbcnt_hi(                 \
                (unsigned)(mask >> 32),                                       \
                __builtin_amdgcn_mbcnt_lo((unsigned)mask, 0));                \
            if (slot < K) snp[slot] = (nn);                                   \
        }                                                                     \
        cnt += (int)__popcll(mask);                                           \
    } while (0)

// ---------------------------------------------------------------------------
// Kernel 1: ball query with the WHOLE batch point cloud staged in LDS.
// 256 blocks x 512 threads; block = (batch via %8 XCD affinity, 64 centers).
// Stage: 8192 points -> LDS float4 {x,y,z,pn^2} (128 KB; pn^2 computed
// inline with exact np op order — prep_points/pointsT deleted).
// Scan: 8 waves x 8 centers each, chunks of 64 points via ds_read_b128
// (conflict-free: consecutive 16 B per lane). Replaces the serial
// L2-latency-bound chase (~200 cyc/load) with ~12 cyc LDS reads; the
// heavy-tailed corner-center scans now cost LDS throughput, not latency.
// Ballot/slot/fill semantics verbatim. Tail writes idx + out1 ch 0..2
// (p - center, identical IEEE ops/operands as the verified R3 version,
// point fetched from LDS instead of pointsT).
// LDS: 128 KB pts + 8 KB sn = 136 KB -> 1 block/CU (2 waves/SIMD), fine:
// loads are LDS-local so little TLP is needed to cover latency.
// ---------------------------------------------------------------------------
__global__ __launch_bounds__(512) void ballquery_kernel(
    const float* __restrict__ points,   // [B,3,N]
    const float* __restrict__ centers,  // [B,3,M]
    int* __restrict__ idx,              // [B,M,K]
    float* __restrict__ out1)           // [B,67,M,K] (writes ch 0..2)
{
    __shared__ float4 pts4[N];          // 128 KB
    __shared__ int    sn[64 * K];       // 8 KB, one row per local center

    const int bid = blockIdx.x;
    const int b   = bid & 7;            // XCD affinity
    const int m0  = (bid >> 3) << 6;    // 64 centers per block
    const int t   = threadIdx.x;

    // ---- stage the point cloud (coalesced; 32 blocks/batch share L2) ----
    {
        const float* pc = points + (size_t)b * 3 * N;
        #pragma unroll
        for (int i = 0; i < 16; ++i) {
            const int n = i * 512 + t;
            const float px = pc[n];
            const float py = pc[N + n];
            const float pz = pc[2 * N + n];
            float4 v;
            v.x = px; v.y = py; v.z = pz;
            v.w = __fadd_rn(__fadd_rn(__fmul_rn(px, px), __fmul_rn(py, py)),
                            __fmul_rn(pz, pz));   // pn^2, np op order
            pts4[n] = v;
        }
    }
    __syncthreads();

    const int wv   = t >> 6;
    const int lane = t & 63;
    const size_t cs = (size_t)M * K;

    for (int k = 0; k < 8; ++k) {
        const int ml = wv * 8 + k;      // local center 0..63
        const int m  = m0 + ml;

        const float cx = rfl(centers[((size_t)b * 3 + 0) * M + m]);
        const float cy = rfl(centers[((size_t)b * 3 + 1) * M + m]);
        const float cz = rfl(centers[((size_t)b * 3 + 2) * M + m]);
        const float cn = rfl(__fadd_rn(
            __fadd_rn(__fmul_rn(cx, cx), __fmul_rn(cy, cy)),
            __fmul_rn(cz, cz)));

        int* snp = &sn[ml * K];
        if (lane == 0) snp[0] = 0;      // default fill for empty ball
        int cnt = 0;

        // scan 128 chunks of 64 points, early-exit check every 256 points
        for (int c = 0; c < 128; c += 4) {
            const float4 v0 = pts4[(c + 0) * 64 + lane];
            const float4 v1 = pts4[(c + 1) * 64 + lane];
            const float4 v2 = pts4[(c + 2) * 64 + lane];
            const float4 v3 = pts4[(c + 3) * 64 + lane];
            PROC(v0, (c + 0) * 64 + lane);
            PROC(v1, (c + 1) * 64 + lane);
            PROC(v2, (c + 2) * 64 + lane);
            PROC(v3, (c + 3) * 64 + lane);
            if (cnt >= K) break;
        }

        // fill slots >= cnt with first valid index (same-wave LDS ordering,
        // identical to the verified kernel), then emit idx + coord channels.
        if (lane < K) {
            const int fill = snp[0];
            const int v    = snp[lane];
            const int nf   = (lane < cnt) ? v : fill;
            idx[((size_t)b * M + m) * K + lane] = nf;

            const float4 p = pts4[nf];
            const size_t o = (size_t)b * 67 * cs + (size_t)m * K + lane;
            __builtin_nontemporal_store(p.x - cx, &out1[o]);
            __builtin_nontemporal_store(p.y - cy, &out1[o + cs]);
            __builtin_nontemporal_store(p.z - cz, &out1[o + 2 * cs]);
        }
    }
}

// ---------------------------------------------------------------------------
// Kernel 2: channel-slab gather — byte-identical to R3 (passed, absmax 0.0).
// Block = (batch, table, channel-pair): stage 2 contiguous channel rows
// (64 KB) in LDS, sweep all M*K positions with random 4 B LDS reads and
// perfectly contiguous float4 NT store streams.
// ---------------------------------------------------------------------------
__global__ __launch_bounds__(512) void gather_kernel(
    const float* __restrict__ temb,     // [B,64,N] natural layout
    const float* __restrict__ feats,    // [B,64,N] natural layout
    const int*   __restrict__ idx,      // [B,M,K]
    float* __restrict__ out1,           // [B,67,M,K] (writes ch 3..66)
    float* __restrict__ out2)           // [B,64,M,K]
{
    __shared__ float row[2 * N];        // 64 KB: two channel rows

    const int bid  = blockIdx.x;
    const int b    = bid & 7;           // XCD affinity (idx[b] hot in XCD-b L2)
    const int slab = bid >> 3;          // 0..63
    const int tab  = slab >> 5;         // 0: feats, 1: temb
    const int c0   = (slab & 31) * 2;   // channel pair
    const int t    = threadIdx.x;

    // stage: channels c0,c0+1 are contiguous in [64][N] layout -> linear copy
    const f4* src4 = (const f4*)((tab ? temb : feats)
                                 + ((size_t)b * 64 + c0) * N);
    f4* lds4 = (f4*)row;
    #pragma unroll
    for (int i = 0; i < 8; ++i)
        lds4[i * 512 + t] = __builtin_nontemporal_load(&src4[i * 512 + t]);
    __syncthreads();

    const size_t cs = (size_t)M * K;
    float* o0 = tab ? (out2 + ((size_t)b * 64 + c0) * cs)
                    : (out1 + ((size_t)b * 67 + 3 + c0) * cs);
    f4* o0v = (f4*)o0;
    f4* o1v = (f4*)(o0 + cs);
    const i4* idx4 = (const i4*)(idx + (size_t)b * M * K);

    // 65536 positions, 4 per thread per iter, 512 threads -> 32 iters.
    // One-deep idx prefetch to hide the (L2-resident) index load.
    i4 nn = idx4[t];
    for (int it = 0; it < 32; ++it) {
        const int q = it * 512 + t;     // int4 / float4 position index
        const i4 cur = nn;
        if (it < 31) nn = idx4[q + 512];
        f4 v0, v1;
        v0.x = row[cur.x];     v0.y = row[cur.y];
        v0.z = row[cur.z];     v0.w = row[cur.w];
        v1.x = row[N + cur.x]; v1.y = row[N + cur.y];
        v1.z = row[N + cur.z]; v1.w = row[N + cur.w];
        __builtin_nontemporal_store(v0, &o0v[q]);
        __builtin_nontemporal_store(v1, &o1v[q]);
    }
}

extern "C" void kernel_launch(void* const* d_in, const int* in_sizes, int n_in,
                              void* d_out, int out_size, void* d_ws, size_t ws_size,
                              hipStream_t stream) {
    const float* points  = (const float*)d_in[0];  // [8,3,8192]
    const float* centers = (const float*)d_in[1];  // [8,3,2048]
    const float* temb    = (const float*)d_in[2];  // [8,64,8192]
    const float* feats   = (const float*)d_in[3];  // [8,64,8192]

    // workspace layout (2 MB)
    int* idxws = (int*)d_ws;                              // [8,2048,32]

    float* out1 = (float*)d_out;                          // [8,67,2048,32]
    float* out2 = out1 + (size_t)B * (3 + C) * M * K;     // [8,64,2048,32]

    ballquery_kernel<<<B * (M / 64), 512, 0, stream>>>(points, centers,
                                                       idxws, out1);
    gather_kernel<<<B * 2 * 32, 512, 0, stream>>>(temb, feats, idxws,
                                                  out1, out2);
}